// Round 2
// baseline (48.684 us; speedup 1.0000x reference)
//
#include <hip/hip_runtime.h>
#include <math.h>

#define NB 256
#define ND 2048
#define T_K 10.0f

// ---------------------------------------------------------------------------
// Kernel 1: per-row mean & std (ddof=1). One block (256 threads) per row.
// 2048 fp32 per row = 2 float4 per thread.
// ---------------------------------------------------------------------------
__global__ __launch_bounds__(256) void stats_kernel(const float* __restrict__ feat,
                                                    float* __restrict__ stats) {
    const int b   = blockIdx.x;
    const int tid = threadIdx.x;
    const float4* row = (const float4*)(feat + (size_t)b * ND);

    float sum = 0.f, sumsq = 0.f;
#pragma unroll
    for (int i = 0; i < 2; ++i) {
        float4 v = row[tid + i * 256];
        sum   += v.x + v.y + v.z + v.w;
        sumsq += v.x * v.x + v.y * v.y + v.z * v.z + v.w * v.w;
    }
    // wave-64 reduce
#pragma unroll
    for (int off = 32; off > 0; off >>= 1) {
        sum   += __shfl_down(sum, off, 64);
        sumsq += __shfl_down(sumsq, off, 64);
    }
    __shared__ float ls[4], lq[4];
    const int lane = tid & 63, wid = tid >> 6;
    if (lane == 0) { ls[wid] = sum; lq[wid] = sumsq; }
    __syncthreads();
    if (tid == 0) {
        float S  = ls[0] + ls[1] + ls[2] + ls[3];
        float Q2 = lq[0] + lq[1] + lq[2] + lq[3];
        float mean = S / (float)ND;
        float var  = (Q2 - S * mean) / (float)(ND - 1);
        var = fmaxf(var, 0.f);
        stats[b]      = mean;
        stats[NB + b] = sqrtf(var);
    }
}

// ---------------------------------------------------------------------------
// Kernel 2: init the 256 min-accumulators to +inf bit pattern.
// ---------------------------------------------------------------------------
__global__ void init_kernel(unsigned int* __restrict__ minbits) {
    minbits[threadIdx.x] = 0x7F800000u;  // +inf
}

// ---------------------------------------------------------------------------
// Kernel 3: brute-force min squared distance scan over the queue.
// Each wave: lane l owns samples b = l, l+64, l+128, l+192 (4 acc regs).
// Wave grid-strides over queue in float4 quads (wave-uniform loads).
// ---------------------------------------------------------------------------
__global__ __launch_bounds__(256) void scan_kernel(const float* __restrict__ mus,
                                                   const float* __restrict__ sigmas,
                                                   const float* __restrict__ stats,
                                                   unsigned int* __restrict__ minbits,
                                                   int Q) {
    const int lane = threadIdx.x & 63;
    const int wid  = threadIdx.x >> 6;

    float m[4], s[4];
#pragma unroll
    for (int k = 0; k < 4; ++k) {
        m[k] = stats[lane + 64 * k];
        s[k] = stats[NB + lane + 64 * k];
    }

    float acc[4];
#pragma unroll
    for (int k = 0; k < 4; ++k) acc[k] = INFINITY;

    const int nquad = Q >> 2;
    const int gw    = blockIdx.x * 4 + wid;
    const int nw    = gridDim.x * 4;
    const float4* mu4 = (const float4*)mus;
    const float4* sg4 = (const float4*)sigmas;

    for (int iq = gw; iq < nquad; iq += nw) {
        float4 mu = mu4[iq];
        float4 sg = sg4[iq];
#pragma unroll
        for (int k = 0; k < 4; ++k) {
            float dm, ds, d;
            dm = m[k] - mu.x; ds = s[k] - sg.x; d = fmaf(ds, ds, dm * dm); acc[k] = fminf(acc[k], d);
            dm = m[k] - mu.y; ds = s[k] - sg.y; d = fmaf(ds, ds, dm * dm); acc[k] = fminf(acc[k], d);
            dm = m[k] - mu.z; ds = s[k] - sg.z; d = fmaf(ds, ds, dm * dm); acc[k] = fminf(acc[k], d);
            dm = m[k] - mu.w; ds = s[k] - sg.w; d = fmaf(ds, ds, dm * dm); acc[k] = fminf(acc[k], d);
        }
    }

    // scalar tail (Q % 4), done once by wave 0 of block 0
    if (gw == 0) {
        for (int q = nquad * 4; q < Q; ++q) {
            float mu = mus[q], sg = sigmas[q];
#pragma unroll
            for (int k = 0; k < 4; ++k) {
                float dm = m[k] - mu, ds = s[k] - sg;
                acc[k] = fminf(acc[k], fmaf(ds, ds, dm * dm));
            }
        }
    }

    // block reduce: 4 waves x 256 b-slots
    __shared__ float red[4][NB];
#pragma unroll
    for (int k = 0; k < 4; ++k) red[wid][lane + 64 * k] = acc[k];
    __syncthreads();

    const int b = threadIdx.x;
    float v = fminf(fminf(red[0][b], red[1][b]), fminf(red[2][b], red[3][b]));
    atomicMin(&minbits[b], __float_as_uint(v));  // nonneg floats: uint order == float order
}

// ---------------------------------------------------------------------------
// Kernel 4: T = exp(-T_k * sqrt(min_sq))
// ---------------------------------------------------------------------------
__global__ void final_kernel(const unsigned int* __restrict__ minbits,
                             float* __restrict__ out) {
    const int b = threadIdx.x;
    float d2 = __uint_as_float(minbits[b]);
    out[b] = expf(-T_K * sqrtf(d2));
}

extern "C" void kernel_launch(void* const* d_in, const int* in_sizes, int n_in,
                              void* d_out, int out_size, void* d_ws, size_t ws_size,
                              hipStream_t stream) {
    const float* features = (const float*)d_in[0];
    // d_in[1]=labels, d_in[2]=pred, d_in[3]=confidence -- unused by reference
    const float* queue_mus    = (const float*)d_in[4];
    const float* queue_sigmas = (const float*)d_in[5];
    const int Q = in_sizes[4];

    float*        stats   = (float*)d_ws;                       // [0..255] means, [256..511] stds
    unsigned int* minbits = (unsigned int*)((float*)d_ws + 2 * NB);

    stats_kernel<<<NB, 256, 0, stream>>>(features, stats);
    init_kernel<<<1, NB, 0, stream>>>(minbits);
    scan_kernel<<<1024, 256, 0, stream>>>(queue_mus, queue_sigmas, stats, minbits, Q);
    final_kernel<<<1, NB, 0, stream>>>(minbits, (float*)d_out);
}